// Round 2
// baseline (512.289 us; speedup 1.0000x reference)
//
#include <hip/hip_runtime.h>

#define B_ 8
#define C_ 512
#define H_ 96
#define W_ 96
#define HW_ (H_ * W_)   // 9216
#define CK_ 64
#define OC_ 128         // key(64) + value(64) fused output channels

// Intermediates live inside d_out (151 MB), zero d_ws usage:
//   y[b][cv][hw]  -> out channels [0..63]   of batch b   (written K2, read K3)
//   kv[b][o][hw]  -> out channels [64..191] of batch b   (written K1, read K2, dead after)
// K3 phase 1 writes ch 128..511 (disjoint from y), phase 2 writes ch 0..127
// where each block reads only its own (b, px-tile) y region, staged to LDS
// behind __syncthreads() before any global store.

// ---------------------------------------------------------------------------
// Kernel 1: fused 1x1 convs -> kv region; o<64: relu(key1), o>=64: value
// ---------------------------------------------------------------------------
__global__ __launch_bounds__(256, 2)
void kv_conv_kernel(const float* __restrict__ x,
                    const float* __restrict__ key1_w, const float* __restrict__ key1_b,
                    const float* __restrict__ value_w, const float* __restrict__ value_b,
                    float* __restrict__ outbuf)
{
    const int b   = blockIdx.y;
    const int px0 = blockIdx.x * 128;
    const int tid = threadIdx.x;
    const int tx  = tid & 15;   // pixel dim
    const int ty  = tid >> 4;   // outch dim

    __shared__ float xs[32][128];   // [k][px]
    __shared__ float ws[32][132];   // [k][outch], padded row

    float acc[8][8];
#pragma unroll
    for (int i = 0; i < 8; ++i)
#pragma unroll
        for (int j = 0; j < 8; ++j) acc[i][j] = 0.f;

    const float* xb = x + (size_t)b * C_ * HW_ + px0;

    for (int kc = 0; kc < C_; kc += 32) {
#pragma unroll
        for (int q = 0; q < 4; ++q) {
            int fid = q * 256 + tid;
            int kk  = fid >> 5;
            int c4  = fid & 31;
            float4 v = *(const float4*)(xb + (size_t)(kc + kk) * HW_ + c4 * 4);
            *(float4*)&xs[kk][c4 * 4] = v;
        }
#pragma unroll
        for (int q = 0; q < 4; ++q) {
            int fid = q * 256 + tid;
            int o   = fid >> 3;
            int c4  = fid & 7;
            const float* wrow = (o < 64) ? (key1_w + o * C_) : (value_w + (o - 64) * C_);
            float4 v = *(const float4*)(wrow + kc + c4 * 4);
            ws[c4 * 4 + 0][o] = v.x;
            ws[c4 * 4 + 1][o] = v.y;
            ws[c4 * 4 + 2][o] = v.z;
            ws[c4 * 4 + 3][o] = v.w;
        }
        __syncthreads();

#pragma unroll 8
        for (int kk = 0; kk < 32; ++kk) {
            float a[8], bv[8];
            *(float4*)&a[0]  = *(const float4*)&ws[kk][ty * 8];
            *(float4*)&a[4]  = *(const float4*)&ws[kk][ty * 8 + 4];
            *(float4*)&bv[0] = *(const float4*)&xs[kk][tx * 4];
            *(float4*)&bv[4] = *(const float4*)&xs[kk][64 + tx * 4];
#pragma unroll
            for (int i = 0; i < 8; ++i)
#pragma unroll
                for (int j = 0; j < 8; ++j)
                    acc[i][j] = fmaf(a[i], bv[j], acc[i][j]);
        }
        __syncthreads();
    }

    // kv[b][o][hw] stored at out channels 64+o of batch b
    float* kvb = outbuf + ((size_t)b * C_ + 64) * HW_ + px0;
#pragma unroll
    for (int i = 0; i < 8; ++i) {
        int o = ty * 8 + i;
        float bias = (o < 64) ? key1_b[o] : value_b[o - 64];
        float4 v0, v1;
        float* p0 = (float*)&v0;
        float* p1 = (float*)&v1;
#pragma unroll
        for (int j = 0; j < 4; ++j) {
            float u0 = acc[i][j] + bias;
            float u1 = acc[i][j + 4] + bias;
            if (o < 64) { u0 = fmaxf(u0, 0.f); u1 = fmaxf(u1, 0.f); }
            p0[j] = u0;
            p1[j] = u1;
        }
        *(float4*)(kvb + (size_t)o * HW_ + tx * 4)      = v0;
        *(float4*)(kvb + (size_t)o * HW_ + 64 + tx * 4) = v1;
    }
}

// ---------------------------------------------------------------------------
// Kernel 2: depthwise 3x3 + key3 1x1 + softmax + 9-tap value aggregation.
// Reads kv region (ch 64..191), writes y region (ch 0..63). Disjoint.
// ---------------------------------------------------------------------------
__global__ __launch_bounds__(256, 4)
void attn_kernel(const float* __restrict__ dw_w, const float* __restrict__ dw_b,
                 const float* __restrict__ k3_w, const float* __restrict__ k3_b,
                 float* __restrict__ outbuf)
{
    const int b  = blockIdx.y;
    const int hw = blockIdx.x * 256 + threadIdx.x;
    const int h  = hw / W_;
    const int w  = hw % W_;

    __shared__ float s_dw[CK_ * 9];
    __shared__ float s_dwb[CK_];
    __shared__ float s_k3[9 * CK_];
    __shared__ float s_k3b[16];

    for (int i = threadIdx.x; i < CK_ * 9; i += 256) {
        s_dw[i] = dw_w[i];
        s_k3[i] = k3_w[i];
    }
    if (threadIdx.x < CK_) s_dwb[threadIdx.x] = dw_b[threadIdx.x];
    if (threadIdx.x < 9)   s_k3b[threadIdx.x] = k3_b[threadIdx.x];
    __syncthreads();

    int  off[9];
    bool valid[9];
#pragma unroll
    for (int t = 0; t < 9; ++t) {
        int dy = t / 3 - 1, dx = t % 3 - 1;
        int hh = h + dy, ww = w + dx;
        valid[t] = (hh >= 0) && (hh < H_) && (ww >= 0) && (ww < W_);
        off[t]   = hh * W_ + ww;
    }

    float logits[9];
#pragma unroll
    for (int t = 0; t < 9; ++t) logits[t] = s_k3b[t];

    const float* kb = outbuf + ((size_t)b * C_ + 64) * HW_;   // key planes
#pragma unroll 4
    for (int c = 0; c < CK_; ++c) {
        const float* kc = kb + (size_t)c * HW_;
        float d = s_dwb[c];
#pragma unroll
        for (int t = 0; t < 9; ++t) {
            float val = valid[t] ? kc[off[t]] : 0.f;
            d = fmaf(s_dw[c * 9 + t], val, d);
        }
#pragma unroll
        for (int t = 0; t < 9; ++t)
            logits[t] = fmaf(s_k3[t * CK_ + c], d, logits[t]);
    }

    float m = logits[0];
#pragma unroll
    for (int t = 1; t < 9; ++t) m = fmaxf(m, logits[t]);
    float e[9], s = 0.f;
#pragma unroll
    for (int t = 0; t < 9; ++t) { e[t] = __expf(logits[t] - m); s += e[t]; }
    float inv = 1.f / s;
    float wt[9];
#pragma unroll
    for (int t = 0; t < 9; ++t) wt[t] = e[t] * inv;

    const float* vb = kb + (size_t)CK_ * HW_;                 // value planes
    float* yb = outbuf + (size_t)b * C_ * HW_;                // y -> ch 0..63
#pragma unroll 4
    for (int cv = 0; cv < CK_; ++cv) {
        const float* vc = vb + (size_t)cv * HW_;
        float acc = 0.f;
#pragma unroll
        for (int t = 0; t < 9; ++t) {
            float val = valid[t] ? vc[off[t]] : 0.f;
            acc = fmaf(wt[t], val, acc);
        }
        yb[(size_t)cv * HW_ + hw] = acc;
    }
}

// ---------------------------------------------------------------------------
// Kernel 3: out = x + out_b + out_w[512x64] @ y.  oc_base selects phase.
// y is read from out channels 0..63 of the SAME (b, px-tile) this block may
// overwrite (phase 2) -- staged to LDS behind __syncthreads before stores.
// NOTE: no __restrict__ on outbuf (y source aliases destination in phase 2).
// ---------------------------------------------------------------------------
__global__ __launch_bounds__(256, 2)
void out_conv_kernel(const float* __restrict__ out_w, const float* __restrict__ out_b,
                     const float* __restrict__ x, float* outbuf, int oc_base)
{
    const int b   = blockIdx.z;
    const int o0  = oc_base + blockIdx.y * 128;
    const int px0 = blockIdx.x * 128;
    const int tid = threadIdx.x;
    const int tx  = tid & 15;
    const int ty  = tid >> 4;

    __shared__ float ys[64][128];   // [cv][px]
    __shared__ float ws[64][132];   // [cv][outch]

    const float* ybp = outbuf + (size_t)b * C_ * HW_ + px0;   // y planes (ch 0..63)
#pragma unroll
    for (int q = 0; q < 8; ++q) {
        int fid = q * 256 + tid;
        int cv  = fid >> 5;
        int c4  = fid & 31;
        *(float4*)&ys[cv][c4 * 4] = *(const float4*)(ybp + (size_t)cv * HW_ + c4 * 4);
    }
#pragma unroll
    for (int q = 0; q < 8; ++q) {
        int fid = q * 256 + tid;
        int o   = fid >> 4;
        int c4  = fid & 15;
        float4 v = *(const float4*)(out_w + (size_t)(o0 + o) * CK_ + c4 * 4);
        ws[c4 * 4 + 0][o] = v.x;
        ws[c4 * 4 + 1][o] = v.y;
        ws[c4 * 4 + 2][o] = v.z;
        ws[c4 * 4 + 3][o] = v.w;
    }
    __syncthreads();   // all y global reads complete before any store below

    float acc[8][8];
#pragma unroll
    for (int i = 0; i < 8; ++i)
#pragma unroll
        for (int j = 0; j < 8; ++j) acc[i][j] = 0.f;

#pragma unroll 8
    for (int kk = 0; kk < 64; ++kk) {
        float a[8], bv[8];
        *(float4*)&a[0]  = *(const float4*)&ws[kk][ty * 8];
        *(float4*)&a[4]  = *(const float4*)&ws[kk][ty * 8 + 4];
        *(float4*)&bv[0] = *(const float4*)&ys[kk][tx * 4];
        *(float4*)&bv[4] = *(const float4*)&ys[kk][64 + tx * 4];
#pragma unroll
        for (int i = 0; i < 8; ++i)
#pragma unroll
            for (int j = 0; j < 8; ++j)
                acc[i][j] = fmaf(a[i], bv[j], acc[i][j]);
    }

    const float* xb = x + (size_t)b * C_ * HW_ + px0;
    float* ob       = outbuf + (size_t)b * C_ * HW_ + px0;
#pragma unroll
    for (int i = 0; i < 8; ++i) {
        int o = o0 + ty * 8 + i;
        float bias = out_b[o];
        float4 x0 = *(const float4*)(xb + (size_t)o * HW_ + tx * 4);
        float4 x1 = *(const float4*)(xb + (size_t)o * HW_ + 64 + tx * 4);
        float4 r0, r1;
        r0.x = acc[i][0] + bias + x0.x;
        r0.y = acc[i][1] + bias + x0.y;
        r0.z = acc[i][2] + bias + x0.z;
        r0.w = acc[i][3] + bias + x0.w;
        r1.x = acc[i][4] + bias + x1.x;
        r1.y = acc[i][5] + bias + x1.y;
        r1.z = acc[i][6] + bias + x1.z;
        r1.w = acc[i][7] + bias + x1.w;
        *(float4*)(ob + (size_t)o * HW_ + tx * 4)      = r0;
        *(float4*)(ob + (size_t)o * HW_ + 64 + tx * 4) = r1;
    }
}

extern "C" void kernel_launch(void* const* d_in, const int* in_sizes, int n_in,
                              void* d_out, int out_size, void* d_ws, size_t ws_size,
                              hipStream_t stream)
{
    const float* x       = (const float*)d_in[0];
    const float* key1_w  = (const float*)d_in[1];
    const float* key1_b  = (const float*)d_in[2];
    const float* dw_w    = (const float*)d_in[3];
    const float* dw_b    = (const float*)d_in[4];
    const float* k3_w    = (const float*)d_in[5];
    const float* k3_b    = (const float*)d_in[6];
    const float* value_w = (const float*)d_in[7];
    const float* value_b = (const float*)d_in[8];
    const float* out_w   = (const float*)d_in[9];
    const float* out_b   = (const float*)d_in[10];
    float* out = (float*)d_out;

    // K1: kv -> out channels 64..191 per batch
    dim3 g1(HW_ / 128, B_);
    kv_conv_kernel<<<g1, dim3(256), 0, stream>>>(x, key1_w, key1_b, value_w, value_b, out);

    // K2: y -> out channels 0..63 per batch (reads kv)
    dim3 g2(HW_ / 256, B_);
    attn_kernel<<<g2, dim3(256), 0, stream>>>(dw_w, dw_b, k3_w, k3_b, out);

    // K3 phase 1: output channels 128..511 (y region untouched)
    dim3 g3(HW_ / 128, 3, B_);
    out_conv_kernel<<<g3, dim3(256), 0, stream>>>(out_w, out_b, x, out, 128);

    // K3 phase 2: output channels 0..127 (each block self-consumes its y tile)
    dim3 g4(HW_ / 128, 1, B_);
    out_conv_kernel<<<g4, dim3(256), 0, stream>>>(out_w, out_b, x, out, 0);
}

// Round 4
// 466.575 us; speedup vs baseline: 1.0980x; 1.0980x over previous
//
#include <hip/hip_runtime.h>

#define B_ 8
#define C_ 512
#define H_ 96
#define W_ 96
#define HW_ (H_ * W_)   // 9216
#define CK_ 64

typedef __attribute__((ext_vector_type(8))) short bf16x8;
typedef __attribute__((ext_vector_type(4))) float f32x4;

__device__ __forceinline__ short f2bf(float f) {
    union { float f; unsigned u; } v; v.f = f;
    unsigned r = v.u + 0x7fffu + ((v.u >> 16) & 1u);
    return (short)(r >> 16);
}

__device__ __forceinline__ bf16x8 cvt8(float4 a, float4 b) {
    bf16x8 s;
    s[0] = f2bf(a.x); s[1] = f2bf(a.y); s[2] = f2bf(a.z); s[3] = f2bf(a.w);
    s[4] = f2bf(b.x); s[5] = f2bf(b.y); s[6] = f2bf(b.z); s[7] = f2bf(b.w);
    return s;
}

// Intermediates live inside d_out (no d_ws usage):
//   y[b][cv][hw]  -> out channels [0..63]   (written K2, read K3)
//   kv[b][o][hw]  -> out channels [64..191] (written K1, read K2, dead after)

// ---------------------------------------------------------------------------
// Kernel 1 (MFMA): kv[o][px] = W[o][c] @ x[c][px];  o<64: relu(key1)+b, else value+b
// Tile: M=128 oc, N=128 px, K=512, BK=32. 4 waves in 2x2 (wm: oc-half, wn: px-half).
// A (W) staged to LDS bf16 k-contiguous; B (x) fragments loaded direct from global.
// ---------------------------------------------------------------------------
__global__ __launch_bounds__(256, 4)
void kv_conv_mfma(const float* __restrict__ x,
                  const float* __restrict__ key1_w, const float* __restrict__ key1_b,
                  const float* __restrict__ value_w, const float* __restrict__ value_b,
                  float* __restrict__ outbuf)
{
    const int b    = blockIdx.y;
    const int px0  = blockIdx.x * 128;
    const int tid  = threadIdx.x;
    const int lane = tid & 63;
    const int w    = tid >> 6;
    const int wm   = w & 1;      // oc half
    const int wn   = w >> 1;     // px half
    const int l15  = lane & 15;
    const int q    = lane >> 4;

    __shared__ short  Ws[128][40];   // [oc][c-chunk] bf16, stride 40 (80 B, 16B-aligned)
    __shared__ float  s_bias[128];

    if (tid < 128) s_bias[tid] = (tid < 64) ? key1_b[tid] : value_b[tid - 64];

    f32x4 acc[4][4];
#pragma unroll
    for (int i = 0; i < 4; ++i)
#pragma unroll
        for (int j = 0; j < 4; ++j) acc[i][j] = (f32x4){0.f, 0.f, 0.f, 0.f};

    const float* xb = x + (size_t)b * C_ * HW_ + px0;

    const int wrow_i = tid >> 1;
    const int c16    = (tid & 1) * 16;
    const float* wrow = (wrow_i < 64) ? (key1_w + wrow_i * C_)
                                      : (value_w + (wrow_i - 64) * C_);

    for (int kc = 0; kc < C_; kc += 32) {
        __syncthreads();   // protect previous iteration's Ws reads
        {
            const float* wp = wrow + kc + c16;
            float4 f0 = *(const float4*)(wp);
            float4 f1 = *(const float4*)(wp + 4);
            float4 f2 = *(const float4*)(wp + 8);
            float4 f3 = *(const float4*)(wp + 12);
            *(bf16x8*)&Ws[wrow_i][c16]     = cvt8(f0, f1);
            *(bf16x8*)&Ws[wrow_i][c16 + 8] = cvt8(f2, f3);
        }
        __syncthreads();

        bf16x8 af[4];
#pragma unroll
        for (int mt = 0; mt < 4; ++mt)
            af[mt] = *(bf16x8*)&Ws[wm * 64 + mt * 16 + l15][q * 8];

        const float* xq = xb + (size_t)(kc + q * 8) * HW_ + wn * 64 + l15;
#pragma unroll
        for (int nt = 0; nt < 4; ++nt) {
            const float* xp = xq + nt * 16;
            bf16x8 bf;
#pragma unroll
            for (int j = 0; j < 8; ++j) bf[j] = f2bf(xp[(size_t)j * HW_]);
#pragma unroll
            for (int mt = 0; mt < 4; ++mt)
                acc[mt][nt] = __builtin_amdgcn_mfma_f32_16x16x32_bf16(af[mt], bf, acc[mt][nt], 0, 0, 0);
        }
    }

    // epilogue: bias (+relu for key half), store to kv region (out ch 64..191)
    float* kvb = outbuf + ((size_t)b * C_ + 64) * HW_ + px0;
#pragma unroll
    for (int mt = 0; mt < 4; ++mt) {
#pragma unroll
        for (int r = 0; r < 4; ++r) {
            int oc = wm * 64 + mt * 16 + q * 4 + r;
            float bias = s_bias[oc];
#pragma unroll
            for (int nt = 0; nt < 4; ++nt) {
                float v = acc[mt][nt][r] + bias;
                if (oc < 64) v = fmaxf(v, 0.f);
                kvb[(size_t)oc * HW_ + wn * 64 + nt * 16 + l15] = v;
            }
        }
    }
}

// ---------------------------------------------------------------------------
// Kernel 2: depthwise 3x3 + key3 1x1 + softmax + 9-tap value aggregation.
// Reads kv (ch 64..191), writes y (ch 0..63). Unchanged from round 2.
// ---------------------------------------------------------------------------
__global__ __launch_bounds__(256, 4)
void attn_kernel(const float* __restrict__ dw_w, const float* __restrict__ dw_b,
                 const float* __restrict__ k3_w, const float* __restrict__ k3_b,
                 float* __restrict__ outbuf)
{
    const int b  = blockIdx.y;
    const int hw = blockIdx.x * 256 + threadIdx.x;
    const int h  = hw / W_;
    const int w  = hw % W_;

    __shared__ float s_dw[CK_ * 9];
    __shared__ float s_dwb[CK_];
    __shared__ float s_k3[9 * CK_];
    __shared__ float s_k3b[16];

    for (int i = threadIdx.x; i < CK_ * 9; i += 256) {
        s_dw[i] = dw_w[i];
        s_k3[i] = k3_w[i];
    }
    if (threadIdx.x < CK_) s_dwb[threadIdx.x] = dw_b[threadIdx.x];
    if (threadIdx.x < 9)   s_k3b[threadIdx.x] = k3_b[threadIdx.x];
    __syncthreads();

    int  off[9];
    bool valid[9];
#pragma unroll
    for (int t = 0; t < 9; ++t) {
        int dy = t / 3 - 1, dx = t % 3 - 1;
        int hh = h + dy, ww = w + dx;
        valid[t] = (hh >= 0) && (hh < H_) && (ww >= 0) && (ww < W_);
        off[t]   = hh * W_ + ww;
    }

    float logits[9];
#pragma unroll
    for (int t = 0; t < 9; ++t) logits[t] = s_k3b[t];

    const float* kb = outbuf + ((size_t)b * C_ + 64) * HW_;
#pragma unroll 4
    for (int c = 0; c < CK_; ++c) {
        const float* kc = kb + (size_t)c * HW_;
        float d = s_dwb[c];
#pragma unroll
        for (int t = 0; t < 9; ++t) {
            float val = valid[t] ? kc[off[t]] : 0.f;
            d = fmaf(s_dw[c * 9 + t], val, d);
        }
#pragma unroll
        for (int t = 0; t < 9; ++t)
            logits[t] = fmaf(s_k3[t * CK_ + c], d, logits[t]);
    }

    float m = logits[0];
#pragma unroll
    for (int t = 1; t < 9; ++t) m = fmaxf(m, logits[t]);
    float e[9], s = 0.f;
#pragma unroll
    for (int t = 0; t < 9; ++t) { e[t] = __expf(logits[t] - m); s += e[t]; }
    float inv = 1.f / s;
    float wt[9];
#pragma unroll
    for (int t = 0; t < 9; ++t) wt[t] = e[t] * inv;

    const float* vb = kb + (size_t)CK_ * HW_;
    float* yb = outbuf + (size_t)b * C_ * HW_;
#pragma unroll 4
    for (int cv = 0; cv < CK_; ++cv) {
        const float* vc = vb + (size_t)cv * HW_;
        float acc = 0.f;
#pragma unroll
        for (int t = 0; t < 9; ++t) {
            float val = valid[t] ? vc[off[t]] : 0.f;
            acc = fmaf(wt[t], val, acc);
        }
        yb[(size_t)cv * HW_ + hw] = acc;
    }
}

// ---------------------------------------------------------------------------
// Kernel 3 (MFMA): out = x + out_b + out_w[512x64] @ y.  M=128/block, K=64, N=128.
// Phase 1: oc 128..511; phase 2: oc 0..127 (y self-consume, guarded by barrier).
// ---------------------------------------------------------------------------
__global__ __launch_bounds__(256, 4)
void out_conv_mfma(const float* __restrict__ out_w, const float* __restrict__ out_b,
                   const float* __restrict__ x, float* outbuf, int oc_base)
{
    const int b    = blockIdx.z;
    const int o0   = oc_base + blockIdx.y * 128;
    const int px0  = blockIdx.x * 128;
    const int tid  = threadIdx.x;
    const int lane = tid & 63;
    const int w    = tid >> 6;
    const int wm   = w & 1;
    const int wn   = w >> 1;
    const int l15  = lane & 15;
    const int q    = lane >> 4;

    __shared__ short Ws[128][72];   // [oc][cv] bf16, stride 72 (144 B, 16B-aligned)
    __shared__ float s_bias[128];

    {   // stage out_w tile (128 x 64) -> bf16 LDS
        int row = tid & 127, half = tid >> 7;            // half selects cv 0..31 / 32..63
        const float* wp = out_w + (size_t)(o0 + row) * CK_ + half * 32;
        float4 f0 = *(const float4*)(wp);
        float4 f1 = *(const float4*)(wp + 4);
        float4 f2 = *(const float4*)(wp + 8);
        float4 f3 = *(const float4*)(wp + 12);
        float4 f4 = *(const float4*)(wp + 16);
        float4 f5 = *(const float4*)(wp + 20);
        float4 f6 = *(const float4*)(wp + 24);
        float4 f7 = *(const float4*)(wp + 28);
        *(bf16x8*)&Ws[row][half * 32]      = cvt8(f0, f1);
        *(bf16x8*)&Ws[row][half * 32 + 8]  = cvt8(f2, f3);
        *(bf16x8*)&Ws[row][half * 32 + 16] = cvt8(f4, f5);
        *(bf16x8*)&Ws[row][half * 32 + 24] = cvt8(f6, f7);
    }
    if (tid < 128) s_bias[tid] = out_b[o0 + tid];
    __syncthreads();

    f32x4 acc[4][4];
#pragma unroll
    for (int i = 0; i < 4; ++i)
#pragma unroll
        for (int j = 0; j < 4; ++j) acc[i][j] = (f32x4){0.f, 0.f, 0.f, 0.f};

    const float* yb = outbuf + (size_t)b * C_ * HW_ + px0;   // y planes ch 0..63

#pragma unroll
    for (int kc = 0; kc < CK_; kc += 32) {
        bf16x8 af[4];
#pragma unroll
        for (int mt = 0; mt < 4; ++mt)
            af[mt] = *(bf16x8*)&Ws[wm * 64 + mt * 16 + l15][kc + q * 8];

        const float* yq = yb + (size_t)(kc + q * 8) * HW_ + wn * 64 + l15;
#pragma unroll
        for (int nt = 0; nt < 4; ++nt) {
            const float* yp = yq + nt * 16;
            bf16x8 bf;
#pragma unroll
            for (int j = 0; j < 8; ++j) bf[j] = f2bf(yp[(size_t)j * HW_]);
#pragma unroll
            for (int mt = 0; mt < 4; ++mt)
                acc[mt][nt] = __builtin_amdgcn_mfma_f32_16x16x32_bf16(af[mt], bf, acc[mt][nt], 0, 0, 0);
        }
    }

    __syncthreads();   // all y reads complete before any store (phase-2 aliasing)

    const float* xb = x + (size_t)b * C_ * HW_ + px0;
    float* ob       = outbuf + (size_t)b * C_ * HW_ + px0;
#pragma unroll
    for (int mt = 0; mt < 4; ++mt) {
#pragma unroll
        for (int r = 0; r < 4; ++r) {
            int ol   = wm * 64 + mt * 16 + q * 4 + r;
            int oc   = o0 + ol;
            float bias = s_bias[ol];
#pragma unroll
            for (int nt = 0; nt < 4; ++nt) {
                size_t idx = (size_t)oc * HW_ + wn * 64 + nt * 16 + l15;
                ob[idx] = acc[mt][nt][r] + bias + xb[idx];
            }
        }
    }
}

extern "C" void kernel_launch(void* const* d_in, const int* in_sizes, int n_in,
                              void* d_out, int out_size, void* d_ws, size_t ws_size,
                              hipStream_t stream)
{
    const float* x       = (const float*)d_in[0];
    const float* key1_w  = (const float*)d_in[1];
    const float* key1_b  = (const float*)d_in[2];
    const float* dw_w    = (const float*)d_in[3];
    const float* dw_b    = (const float*)d_in[4];
    const float* k3_w    = (const float*)d_in[5];
    const float* k3_b    = (const float*)d_in[6];
    const float* value_w = (const float*)d_in[7];
    const float* value_b = (const float*)d_in[8];
    const float* out_w   = (const float*)d_in[9];
    const float* out_b   = (const float*)d_in[10];
    float* out = (float*)d_out;

    dim3 g1(HW_ / 128, B_);
    kv_conv_mfma<<<g1, dim3(256), 0, stream>>>(x, key1_w, key1_b, value_w, value_b, out);

    dim3 g2(HW_ / 256, B_);
    attn_kernel<<<g2, dim3(256), 0, stream>>>(dw_w, dw_b, k3_w, k3_b, out);

    dim3 g3(HW_ / 128, 3, B_);
    out_conv_mfma<<<g3, dim3(256), 0, stream>>>(out_w, out_b, x, out, 128);

    dim3 g4(HW_ / 128, 1, B_);
    out_conv_mfma<<<g4, dim3(256), 0, stream>>>(out_w, out_b, x, out, 0);
}